// Round 7
// baseline (217.813 us; speedup 1.0000x reference)
//
#include <hip/hip_runtime.h>
#include <cstdint>

// ModConv: y[b,o,l] = sum_{i,k} bw[b,o,i,k] * x[b,i,l+k-1],
//   bw = conv_w * s[b,i] * demod[b,o],  s = t@mod_w^T + mod_b + 1,
//   demod = rsqrt(sum_{i,k} (conv_w*s)^2 + 1e-8)
// Proven-parts build: A-fragments (modulated weights) in registers (round 5
// math, absmax-verified), X^T double-buffered in LDS (2 x 130 x 256B = 67KB),
// round-2 schedule (issue loads before MFMA, write-stage after the barrier),
// one __syncthreads per tile. No inline asm. 512 thr / 8 waves (4m x 2n).
// launch_bounds(512,4): VGPR<=128 -> 2 blocks/CU (hard-live ~96+temps).
// 4 o-tile partner blocks of one (b,chunk) share an XCD for x L2 reuse.

namespace {
constexpr int NI = 128, NO = 256, NK = 3, NT = 256, NL = 8192;
constexpr int BM = 64, BN = 128, TPB = 8;     // block: 64 o x 1024 l
constexpr int BUF = 130 * 256;                // 33280 B per X^T buffer
constexpr int S_OFF = 2 * BUF;                // 66560
constexpr int SMEM_BYTES = S_OFF + 512;       // 67072
}

typedef __attribute__((ext_vector_type(8))) short bf16x8;
typedef __attribute__((ext_vector_type(4))) float f32x4;

__device__ __forceinline__ uint32_t f2bf(float f) {
    uint32_t u = __builtin_bit_cast(uint32_t, f);
    return (u + 0x7fffu + ((u >> 16) & 1u)) >> 16;   // RNE
}

__launch_bounds__(512, 4)
__global__ void modconv(const float* __restrict__ x,
                        const float* __restrict__ tvec,
                        const float* __restrict__ conv_w,
                        const float* __restrict__ mod_w,
                        const float* __restrict__ mod_b,
                        float* __restrict__ out) {
    __shared__ __align__(16) char smem[SMEM_BYTES];
    float* s_sh = reinterpret_cast<float*>(smem + S_OFF);

    const int tid = threadIdx.x;

    // 4 o-tile partner blocks of one (b,chunk) share bid&7 (XCD) for x reuse
    const int bid  = blockIdx.x;
    const int slot = bid >> 3;                    // [0,64)
    const int m    = slot & 3;                    // o-tile
    const int g    = (bid & 7) + 8 * (slot >> 2); // [0,128) = (b,chunk)
    const int b     = g >> 3;
    const int chunk = g & 7;
    const int o0    = m * BM;
    const int C     = chunk * (TPB * BN);

    const float* xb = x + (size_t)b * NI * NL;
    float* outb     = out + ((size_t)b * NO + o0) * NL;

    const int lrow = tid & 31, ig = tid >> 5;
    float xr[4][8];                               // one staged tile

    // rows r=2+p*32+lrow <-> cols l0t+1+p*32+lrow; zero-fill col>=NL (chunk 7)
    auto issueL = [&](int l0t) {
        #pragma unroll
        for (int p = 0; p < 4; ++p) {
            const int col = l0t + 1 + p * 32 + lrow;
            const bool ok = col < NL;
            const float* px = xb + (size_t)(ig * 8) * NL + (ok ? col : NL - 1);
            #pragma unroll
            for (int n = 0; n < 8; ++n) xr[p][n] = ok ? px[(size_t)n * NL] : 0.f;
        }
    };
    auto writeS = [&](char* buf) {
        #pragma unroll
        for (int p = 0; p < 4; ++p) {
            const int r = 2 + p * 32 + lrow;
            uint32_t d0 = f2bf(xr[p][0]) | (f2bf(xr[p][1]) << 16);
            uint32_t d1 = f2bf(xr[p][2]) | (f2bf(xr[p][3]) << 16);
            uint32_t d2 = f2bf(xr[p][4]) | (f2bf(xr[p][5]) << 16);
            uint32_t d3 = f2bf(xr[p][6]) | (f2bf(xr[p][7]) << 16);
            *reinterpret_cast<uint4*>(
                buf + r * 256 + ((ig * 16) ^ ((r & 15) << 4))) =
                make_uint4(d0, d1, d2, d3);
        }
    };

    // ---- s[i] = dot(t[b], mod_w[i]) + mod_b[i] + 1   (4 thr/i, f32)
    {
        const int i = tid >> 2, q = tid & 3;
        const float* tp = tvec + b * NT + q * 64;
        const float* mp = mod_w + (size_t)i * NT + q * 64;
        float acc = 0.f;
        #pragma unroll 8
        for (int j = 0; j < 64; ++j) acc = fmaf(tp[j], mp[j], acc);
        acc += __shfl_xor(acc, 1);
        acc += __shfl_xor(acc, 2);
        if (q == 0) s_sh[i] = acc + mod_b[i] + 1.0f;
    }
    __syncthreads();

    const int lane = tid & 63, wid = tid >> 6;
    const int wm = wid >> 1, wn = wid & 1;     // 4m x 2n waves, 16o x 64l each
    const int l16 = lane & 15, lg4 = lane >> 4;
    const int o_l = wm * 16 + l16;

    // ---- per-lane demod (exact f32; union over lg4 slices via shfl)
    float dmod;
    {
        float part = 0.f;
        #pragma unroll
        for (int kc = 0; kc < 4; ++kc) {
            const int i0 = kc * 32 + lg4 * 8;
            const f32x4* wp4 = reinterpret_cast<const f32x4*>(
                conv_w + ((size_t)(o0 + o_l) * NI + i0) * NK);
            f32x4 w4[6];
            #pragma unroll
            for (int q = 0; q < 6; ++q) w4[q] = wp4[q];
            #pragma unroll
            for (int j = 0; j < 8; ++j) {
                const float sj = s_sh[i0 + j];
                const float w0 = w4[(j * 3 + 0) >> 2][(j * 3 + 0) & 3];
                const float w1 = w4[(j * 3 + 1) >> 2][(j * 3 + 1) & 3];
                const float w2 = w4[(j * 3 + 2) >> 2][(j * 3 + 2) & 3];
                part = fmaf(sj * sj, w0 * w0 + w1 * w1 + w2 * w2, part);
            }
        }
        part += __shfl_xor(part, 16);
        part += __shfl_xor(part, 32);
        dmod = rsqrtf(part + 1e-8f);
    }

    // ---- A fragments in registers: afr[k][kc] = bw[o_l][i-slice][k] (bf16)
    bf16x8 afr[3][4];
    #pragma unroll
    for (int kc = 0; kc < 4; ++kc) {
        const int i0 = kc * 32 + lg4 * 8;
        const f32x4* wp4 = reinterpret_cast<const f32x4*>(
            conv_w + ((size_t)(o0 + o_l) * NI + i0) * NK);
        f32x4 w4[6];
        #pragma unroll
        for (int q = 0; q < 6; ++q) w4[q] = wp4[q];
        #pragma unroll
        for (int j = 0; j < 8; ++j) {
            const float sd = s_sh[i0 + j] * dmod;
            #pragma unroll
            for (int k = 0; k < 3; ++k)
                afr[k][kc][j] =
                    (short)f2bf(w4[(j * 3 + k) >> 2][(j * 3 + k) & 3] * sd);
        }
    }

    // ---- tile-0 halo rows 0,1 (cols C-1, C); C-1 < 0 only for chunk 0
    if (tid < 256) {
        const int i = tid >> 1, wq = tid & 1;
        const int col = C - 1 + wq;
        const float v = (col >= 0) ? xb[(size_t)i * NL + col] : 0.f;
        *reinterpret_cast<uint16_t*>(smem + wq * 256 + ((2 * i) ^ (wq << 4))) =
            (uint16_t)f2bf(v);
    }

    issueL(C);           // tile 0
    writeS(smem);        // buf0 rows 2..129
    issueL(C + BN);      // tile 1 in flight across the barrier
    __syncthreads();

    char* rb = smem;
    char* wb = smem + BUF;

    #pragma unroll 1
    for (int t = 0; t < TPB; ++t) {
        const int l0 = C + t * BN;

        if (t + 1 < TPB) {
            // halo: rb rows 128,129 -> wb rows 0,1 (phases 0,1 match; keep XOR)
            if (tid < 32) {
                const int r01 = tid >> 4, c16 = tid & 15;
                const int off = (c16 * 16) ^ (r01 << 4);
                *reinterpret_cast<uint4*>(wb + r01 * 256 + off) =
                    *reinterpret_cast<const uint4*>(
                        rb + (128 + r01) * 256 + off);
            }
            writeS(wb);                          // consumes xr (tile t+1)
        }
        if (t + 2 < TPB) issueL(l0 + 2 * BN);    // next loads fly under MFMA

        f32x4 acc[4];
        const f32x4 zero = {0.f, 0.f, 0.f, 0.f};
        #pragma unroll
        for (int fn = 0; fn < 4; ++fn) acc[fn] = zero;

        __builtin_amdgcn_s_setprio(1);
        #pragma unroll
        for (int k = 0; k < 3; ++k) {
            #pragma unroll
            for (int kc = 0; kc < 4; ++kc) {
                const int cb = kc * 64 + lg4 * 16;
                #pragma unroll
                for (int fn = 0; fn < 4; ++fn) {
                    const int r = wn * 64 + fn * 16 + l16 + k;   // halo shift
                    const bf16x8 bfr = *reinterpret_cast<const bf16x8*>(
                        rb + r * 256 + (cb ^ ((r & 15) << 4)));
                    acc[fn] = __builtin_amdgcn_mfma_f32_16x16x32_bf16(
                        afr[k][kc], bfr, acc[fn], 0, 0, 0);
                }
            }
        }
        __builtin_amdgcn_s_setprio(0);

        // C store: row = wm*16+lg4*4+j, col = l0+wn*64+fn*16+l16
        #pragma unroll
        for (int fn = 0; fn < 4; ++fn) {
            const int colg = l0 + wn * 64 + fn * 16 + l16;
            const int og = wm * 16 + lg4 * 4;
            #pragma unroll
            for (int j = 0; j < 4; ++j)
                __builtin_nontemporal_store(
                    acc[fn][j], &outb[(size_t)(og + j) * NL + colg]);
        }

        __syncthreads();
        { char* tmp = rb; rb = wb; wb = tmp; }
    }
}

extern "C" void kernel_launch(void* const* d_in, const int* in_sizes, int n_in,
                              void* d_out, int out_size, void* d_ws, size_t ws_size,
                              hipStream_t stream) {
    const float* x      = (const float*)d_in[0];
    const float* t      = (const float*)d_in[1];
    const float* conv_w = (const float*)d_in[2];
    const float* mod_w  = (const float*)d_in[3];
    const float* mod_b  = (const float*)d_in[4];

    // 4 o-tiles x 8 chunks x 16 b = 512 blocks, target 2 per CU
    modconv<<<dim3(512), dim3(512), 0, stream>>>(x, t, conv_w, mod_w, mod_b,
                                                 (float*)d_out);
}

// Round 8
// 83.339 us; speedup vs baseline: 2.6136x; 2.6136x over previous
//
#include <hip/hip_runtime.h>
#include <cstdint>

// ModConv: y[b,o,l] = sum_{i,k} bw[b,o,i,k] * x[b,i,l+k-1],
//   bw = conv_w * s[b,i] * demod[b,o],  s = t@mod_w^T + mod_b + 1,
//   demod = rsqrt(sum_{i,k} (conv_w*s)^2 + 1e-8)
// Base = round-2 65us kernel (A-tile in LDS, 130-row X^T, reg-staged loads,
// 512 thr / 8 waves). Surgical change: in-loop __syncthreads() replaced with
// lgkmcnt-only raw barriers so the per-tile barrier no longer drains the
// 64KB of C-stores + staging loads to HBM (hipcc emits vmcnt(0) expcnt(0)
// before s_barrier for __syncthreads). C-stores now nontemporal.

namespace {
constexpr int NB = 16, NI = 128, NO = 256, NK = 3, NT = 256, NL = 8192;
constexpr int BM = 128, BN = 128;
constexpr int TPB = 8;                        // tiles per block (8*128 = 1024 cols)
constexpr int XT_OFF = 3 * 128 * 256;         // A: 3 taps * 128 o * 256B = 98304
constexpr int XT_ROWS = 130;                  // BN + 2 halo
constexpr int SMEM_BYTES = XT_OFF + XT_ROWS * 256;   // 131584 <= 163840
constexpr int NPASS = 5;                      // ceil(130/32) staging passes
}

typedef __attribute__((ext_vector_type(8))) short bf16x8;
typedef __attribute__((ext_vector_type(4))) float f32x4;

__device__ __forceinline__ uint32_t f2bf(float f) {
    uint32_t u = __builtin_bit_cast(uint32_t, f);
    return (u + 0x7fffu + ((u >> 16) & 1u)) >> 16;   // RNE
}

// barrier with LDS-only consistency: do NOT drain global loads/stores
__device__ __forceinline__ void lds_barrier() {
    asm volatile("s_waitcnt lgkmcnt(0)" ::: "memory");
    __builtin_amdgcn_s_barrier();
    __builtin_amdgcn_sched_barrier(0);
}

__launch_bounds__(512, 2)
__global__ void modconv(const float* __restrict__ x,
                        const float* __restrict__ tvec,
                        const float* __restrict__ conv_w,
                        const float* __restrict__ mod_w,
                        const float* __restrict__ mod_b,
                        float* __restrict__ out) {
    __shared__ __align__(16) char smem[SMEM_BYTES];
    // s/d scratch lives in the (not yet used) XT region
    float* s_sh = reinterpret_cast<float*>(smem + XT_OFF);
    float* d_sh = reinterpret_cast<float*>(smem + XT_OFF + 512);

    const int tid = threadIdx.x;

    // ---- XCD-paired block decode: both o-tiles of one (b,chunk) share bid&7
    const int bid  = blockIdx.x;
    const int xcd  = bid & 7;
    const int slot = bid >> 3;          // [0,32)
    const int g    = xcd + 8 * (slot >> 1);   // [0,128): (b,chunk) group
    const int m    = slot & 1;                // o-tile
    const int b     = g >> 3;
    const int chunk = g & 7;
    const int o0    = m * BM;

    const float* xb = x + (size_t)b * NI * NL;
    float* outb     = out + ((size_t)b * NO + o0) * NL;

    // ---- phase 1: s[i] = dot(t[b], mod_w[i]) + mod_b[i] + 1  (4 thr/i)
    {
        const int i = tid >> 2, q = tid & 3;
        const float* tp = tvec + b * NT + q * 64;
        const float* mp = mod_w + i * NT + q * 64;
        float acc = 0.f;
        #pragma unroll 8
        for (int j = 0; j < 64; ++j) acc = fmaf(tp[j], mp[j], acc);
        acc += __shfl_xor(acc, 1);
        acc += __shfl_xor(acc, 2);
        if (q == 0) s_sh[i] = acc + mod_b[i] + 1.0f;
    }
    __syncthreads();

    // ---- phase 2: demod[o] = rsqrt(sum_i s^2 * sum_k w^2 + 1e-8)  (4 thr/o)
    {
        const int o_l = tid >> 2, q = tid & 3;
        const float* cw = conv_w + (size_t)(o0 + o_l) * (NI * NK) + q * 32 * NK;
        float sum = 0.f;
        #pragma unroll 4
        for (int ii = 0; ii < 32; ++ii) {
            float s  = s_sh[q * 32 + ii];
            float w0 = cw[ii * 3 + 0], w1 = cw[ii * 3 + 1], w2 = cw[ii * 3 + 2];
            sum = fmaf(s * s, w0 * w0 + w1 * w1 + w2 * w2, sum);
        }
        sum += __shfl_xor(sum, 1);
        sum += __shfl_xor(sum, 2);
        if (q == 0) d_sh[o_l] = rsqrtf(sum + 1e-8f);
    }
    __syncthreads();

    // ---- staged X loads (tile data held in regs between issue and ds_write)
    float xr[NPASS][8];
    const int lrow = tid & 31;           // row-within-pass (consecutive lanes
    const int ig   = tid >> 5;           //   -> consecutive l: coalesced)

    auto issue_loads = [&](int l0s) {
        #pragma unroll
        for (int p = 0; p < NPASS; ++p) {
            const int r  = p * 32 + lrow;
            const int lg = l0s - 1 + r;
            const bool ok = (r < XT_ROWS) && (lg >= 0) && (lg < NL);
            const float* px = xb + (size_t)(ig * 8) * NL + lg;
            #pragma unroll
            for (int n = 0; n < 8; ++n)
                xr[p][n] = ok ? px[(size_t)n * NL] : 0.0f;
        }
    };
    auto write_stage = [&]() {
        #pragma unroll
        for (int p = 0; p < NPASS; ++p) {
            const int r = p * 32 + lrow;
            if (r < XT_ROWS) {
                uint32_t d0 = f2bf(xr[p][0]) | (f2bf(xr[p][1]) << 16);
                uint32_t d1 = f2bf(xr[p][2]) | (f2bf(xr[p][3]) << 16);
                uint32_t d2 = f2bf(xr[p][4]) | (f2bf(xr[p][5]) << 16);
                uint32_t d3 = f2bf(xr[p][6]) | (f2bf(xr[p][7]) << 16);
                *reinterpret_cast<uint4*>(
                    smem + XT_OFF + r * 256 + ((ig * 16) ^ ((r & 15) << 4))) =
                    make_uint4(d0, d1, d2, d3);
            }
        }
    };

    const int l0_base = chunk * TPB * BN;
    issue_loads(l0_base);   // tile-0 loads fly under the A-fill compute

    // ---- phase 3: A tile (modulated+demodulated weights) -> LDS bf16
    //      byte(k,o,i) = k*32768 + o*256 + ((i*2) ^ ((o&15)<<4)), 2 i per write
    for (int idx = tid; idx < BM * (NI / 2); idx += 512) {
        const int i2 = idx & 63, o = idx >> 6;
        const float* cw = conv_w + ((size_t)(o0 + o) * NI + i2 * 2) * NK;
        const float dm = d_sh[o];
        const float mA = s_sh[i2 * 2] * dm, mB = s_sh[i2 * 2 + 1] * dm;
        const int base = o * 256, sw = (o & 15) << 4;
        #pragma unroll
        for (int k = 0; k < NK; ++k) {
            uint32_t v = f2bf(cw[k] * mA) | (f2bf(cw[k + NK] * mB) << 16);
            *reinterpret_cast<uint32_t*>(
                smem + k * 32768 + base + ((i2 * 4) ^ sw)) = v;
        }
    }
    // A made visible by the first in-loop barrier

    const int lane = tid & 63;
    const int wid  = tid >> 6;
    const int wm   = wid >> 2, wn = wid & 3;   // 2x4 waves: 64x32 out each
    const int l16  = lane & 15, lg4 = lane >> 4;

    for (int tile = 0; tile < TPB; ++tile) {
        const int l0 = l0_base + tile * BN;
        lds_barrier();     // previous tile's LDS reads done -> Xt reusable

        write_stage();     // XT <- tile t (vmcnt waits inserted per-use)
        lds_barrier();     // XT visible to all waves

        if (tile + 1 < TPB) issue_loads(l0 + BN);   // t+1 loads fly under MFMA

        // ---- MFMA: 3 taps x 4 K-chunks; wave tile 64(o) x 32(l)
        f32x4 acc[4][2];
        const f32x4 zero = {0.f, 0.f, 0.f, 0.f};
        #pragma unroll
        for (int fm = 0; fm < 4; ++fm)
            #pragma unroll
            for (int fn = 0; fn < 2; ++fn) acc[fm][fn] = zero;

        #pragma unroll
        for (int k = 0; k < NK; ++k) {
            #pragma unroll
            for (int kc = 0; kc < 4; ++kc) {
                const int cb = kc * 64 + lg4 * 16;
                bf16x8 af[4], bfr[2];
                #pragma unroll
                for (int fm = 0; fm < 4; ++fm) {
                    const int o = wm * 64 + fm * 16 + l16;
                    af[fm] = *reinterpret_cast<const bf16x8*>(
                        smem + k * 32768 + o * 256 + (cb ^ ((o & 15) << 4)));
                }
                #pragma unroll
                for (int fn = 0; fn < 2; ++fn) {
                    const int r = wn * 32 + fn * 16 + l16 + k;
                    bfr[fn] = *reinterpret_cast<const bf16x8*>(
                        smem + XT_OFF + r * 256 + (cb ^ ((r & 15) << 4)));
                }
                #pragma unroll
                for (int fm = 0; fm < 4; ++fm)
                    #pragma unroll
                    for (int fn = 0; fn < 2; ++fn)
                        acc[fm][fn] = __builtin_amdgcn_mfma_f32_16x16x32_bf16(
                            af[fm], bfr[fn], acc[fm][fn], 0, 0, 0);
            }
        }

        // ---- write C (f32, nontemporal): row = lg4*4 + j within fragment
        #pragma unroll
        for (int fm = 0; fm < 4; ++fm) {
            #pragma unroll
            for (int fn = 0; fn < 2; ++fn) {
                const int og = wm * 64 + fm * 16 + lg4 * 4;
                const int lg = l0 + wn * 32 + fn * 16 + l16;
                #pragma unroll
                for (int j = 0; j < 4; ++j)
                    __builtin_nontemporal_store(
                        acc[fm][fn][j], &outb[(size_t)(og + j) * NL + lg]);
            }
        }
    }
}

extern "C" void kernel_launch(void* const* d_in, const int* in_sizes, int n_in,
                              void* d_out, int out_size, void* d_ws, size_t ws_size,
                              hipStream_t stream) {
    const float* x      = (const float*)d_in[0];
    const float* t      = (const float*)d_in[1];
    const float* conv_w = (const float*)d_in[2];
    const float* mod_w  = (const float*)d_in[3];
    const float* mod_b  = (const float*)d_in[4];

    modconv<<<dim3(256), dim3(512), 0, stream>>>(x, t, conv_w, mod_w, mod_b,
                                                 (float*)d_out);
}